// Round 5
// baseline (213.037 us; speedup 1.0000x reference)
//
#include <hip/hip_runtime.h>

// Haar forward: input (B=8, C=64, H=512, W=512) fp32 NCHW
// output (B, 4*C, 256, 256), subband-major.
// Per 2x2 block {a,b,c,d}: LL=.25(a+b+c+d), k1=.25(a-b+c-d), k2=.25(a+b-c-d), k3=.25(a-b-c+d)
//
// R5: LDS-bounced version for full per-instruction memory density.
//  - Load phase: 4 dense nt float4 loads/thread (1 KiB/wave/instr) -> LDS,
//    deinterleave swizzle (even chunk -> pos c/2, odd chunk -> pos 64+c/2 in row)
//    so compute reads are dense 16 B/lane ds_read_b128 (conflict-free).
//  - Compute: thread = 8 input cols x 2 rows -> float4 per subband.
//  - Store: 4 dense nt float4 stores (1 KiB/wave/instr per plane), as R4.

constexpr int B  = 8;
constexpr int C  = 64;
constexpr int H  = 512;
constexpr int W  = 512;
constexpr int HO = H / 2;   // 256
constexpr int WO = W / 2;   // 256
constexpr int RPB  = 4;     // row-pairs per block
constexpr int ROWS = 2 * RPB;            // 8 input rows per block
constexpr int CHUNKS = ROWS * W / 4;     // 1024 float4 chunks per block

typedef float f32x4 __attribute__((ext_vector_type(4)));

__global__ __launch_bounds__(256) void haar_fwd(const float* __restrict__ x,
                                                float* __restrict__ y) {
    __shared__ float lds[ROWS * W];      // 16 KiB

    const int t  = threadIdx.x;
    const int ig = blockIdx.x & 63;      // row-group within image (4 row-pairs)
    const int m  = blockIdx.x >> 6;      // image index b*C + c (0..511)

    const float* src = x + ((size_t)m * H + (size_t)ig * ROWS) * W;

    // ---- Load phase: dense global reads, deinterleaved LDS writes ----
    #pragma unroll
    for (int k = 0; k < 4; ++k) {
        const int ch  = t + k * 256;                 // 0..1023, dense per wave
        const f32x4 v = __builtin_nontemporal_load(
            reinterpret_cast<const f32x4*>(src + 4 * (size_t)ch));
        const int row = ch >> 7;                     // input row 0..7
        const int c   = ch & 127;                    // chunk within row
        const int pos = (c >> 1) + ((c & 1) << 6);   // deinterleave: even->0..63, odd->64..127
        *reinterpret_cast<f32x4*>(&lds[row * W + 4 * pos]) = v;
    }
    __syncthreads();

    // ---- Compute phase: thread -> (row-pair rp, col-block j4) ----
    const int j4 = t & 63;               // 0..63 -> input cols [8*j4, 8*j4+8)
    const int rp = t >> 6;               // 0..3

    // even chunks (cols 8j4..8j4+4) live at pos j4; odd (cols 8j4+4..8j4+8) at pos 64+j4
    const float* l0 = &lds[(2 * rp) * W];
    const float* l1 = l0 + W;
    const f32x4 r0a = *reinterpret_cast<const f32x4*>(l0 + 4 * j4);
    const f32x4 r0b = *reinterpret_cast<const f32x4*>(l0 + 4 * (64 + j4));
    const f32x4 r1a = *reinterpret_cast<const f32x4*>(l1 + 4 * j4);
    const f32x4 r1b = *reinterpret_cast<const f32x4*>(l1 + 4 * (64 + j4));

    const float a0 = r0a.x, b0 = r0a.y, a1 = r0a.z, b1 = r0a.w;
    const float a2 = r0b.x, b2 = r0b.y, a3 = r0b.z, b3 = r0b.w;
    const float c0 = r1a.x, d0 = r1a.y, c1 = r1a.z, d1 = r1a.w;
    const float c2 = r1b.x, d2 = r1b.y, c3 = r1b.z, d3 = r1b.w;

    f32x4 ll, k1, k2, k3;
    ll.x = 0.25f * (a0 + b0 + c0 + d0);
    ll.y = 0.25f * (a1 + b1 + c1 + d1);
    ll.z = 0.25f * (a2 + b2 + c2 + d2);
    ll.w = 0.25f * (a3 + b3 + c3 + d3);

    k1.x = 0.25f * (a0 - b0 + c0 - d0);
    k1.y = 0.25f * (a1 - b1 + c1 - d1);
    k1.z = 0.25f * (a2 - b2 + c2 - d2);
    k1.w = 0.25f * (a3 - b3 + c3 - d3);

    k2.x = 0.25f * (a0 + b0 - c0 - d0);
    k2.y = 0.25f * (a1 + b1 - c1 - d1);
    k2.z = 0.25f * (a2 + b2 - c2 - d2);
    k2.w = 0.25f * (a3 + b3 - c3 - d3);

    k3.x = 0.25f * (a0 - b0 - c0 + d0);
    k3.y = 0.25f * (a1 - b1 - c1 + d1);
    k3.z = 0.25f * (a2 - b2 - c2 + d2);
    k3.w = 0.25f * (a3 - b3 - c3 + d3);

    const int i = ig * RPB + rp;         // output row 0..255
    const size_t plane  = (size_t)HO * WO;
    const size_t rowoff = (size_t)i * WO + 4 * (size_t)j4;
    float* yb = y + ((size_t)(m >> 6) * 4 * C + (m & (C - 1))) * plane + rowoff;

    __builtin_nontemporal_store(ll, reinterpret_cast<f32x4*>(yb));
    __builtin_nontemporal_store(k1, reinterpret_cast<f32x4*>(yb + (size_t)C * plane));
    __builtin_nontemporal_store(k2, reinterpret_cast<f32x4*>(yb + (size_t)2 * C * plane));
    __builtin_nontemporal_store(k3, reinterpret_cast<f32x4*>(yb + (size_t)3 * C * plane));
}

extern "C" void kernel_launch(void* const* d_in, const int* in_sizes, int n_in,
                              void* d_out, int out_size, void* d_ws, size_t ws_size,
                              hipStream_t stream) {
    const float* x = (const float*)d_in[0];
    float* y = (float*)d_out;

    const int blocks = B * C * (HO / RPB);   // 512 * 64 = 32768
    haar_fwd<<<blocks, 256, 0, stream>>>(x, y);
}